// Round 3
// baseline (156.058 us; speedup 1.0000x reference)
//
#include <hip/hip_runtime.h>
#include <hip/hip_bf16.h>
#include <math.h>

typedef __attribute__((ext_vector_type(4))) float f32x4;
typedef __attribute__((ext_vector_type(8))) short bf16x8;
typedef __attribute__((ext_vector_type(4))) int i32x4;

#define NB 2
#define NH 12
#define NS 2048
#define ND 64
#define NKER 9
#define BH (NB*NH)
#define BHS (NB*NH*NS)

using bf16 = __hip_bfloat16;

__device__ __forceinline__ f32x4 mfma16x16x32_bf16(bf16x8 a, bf16x8 b, f32x4 c) {
  return __builtin_amdgcn_mfma_f32_16x16x32_bf16(a, b, c, 0, 0, 0);
}

// ---------------------------------------------------------------------------
// L2-normalize Q and K rows -> bf16. One wave per 64-elem row (lane == d).
// ---------------------------------------------------------------------------
__global__ void normalize_qk(const float* __restrict__ Q, const float* __restrict__ K,
                             bf16* __restrict__ Qn, bf16* __restrict__ Kn) {
  int wid  = (blockIdx.x * blockDim.x + threadIdx.x) >> 6;
  int lane = threadIdx.x & 63;
  if (wid >= 2 * BHS) return;
  const float* src; bf16* dst; int row;
  if (wid < BHS) { src = Q; dst = Qn; row = wid; }
  else           { src = K; dst = Kn; row = wid - BHS; }
  float v  = src[(size_t)row * ND + lane];
  float ss = v * v;
  #pragma unroll
  for (int m = 1; m < 64; m <<= 1) ss += __shfl_xor(ss, m);
  float scale = 1.0f / fmaxf(sqrtf(ss), 1e-12f);
  dst[(size_t)row * ND + lane] = __float2bfloat16(v * scale);
}

// ---------------------------------------------------------------------------
// Vm^T: (V * key-mask) transposed to [BH][D][S] in bf16.
// ---------------------------------------------------------------------------
__global__ void transpose_v(const float* __restrict__ V, const float* __restrict__ mask,
                            bf16* __restrict__ Vmt) {
  __shared__ bf16 tile[64][72];   // padded
  int bh = blockIdx.y;
  int b  = bh / NH;
  int s0 = blockIdx.x * 64;
  int tid = threadIdx.x;

  const float* src = V + ((size_t)bh * NS + s0) * ND;
  int r  = tid >> 2;
  int c0 = (tid & 3) * 16;
  float m = mask[b * NS + s0 + r];
  #pragma unroll
  for (int j = 0; j < 16; ++j)
    tile[r][c0 + j] = __float2bfloat16(src[(size_t)r * ND + c0 + j] * m);
  __syncthreads();

  bf16* dst = Vmt + (size_t)bh * ND * NS + s0;
  int d   = tid >> 2;
  int sc0 = (tid & 3) * 16;
  #pragma unroll
  for (int j = 0; j < 16; ++j)
    dst[(size_t)d * NS + sc0 + j] = tile[sc0 + j][d];
}

// ---------------------------------------------------------------------------
// Depthwise conv over seq axis (kernel 9), writes d_out (initialization).
// ---------------------------------------------------------------------------
__global__ void conv_kernel(const float* __restrict__ V, const float* __restrict__ mask,
                            const float* __restrict__ cw, float* __restrict__ out) {
  int idx = blockIdx.x * blockDim.x + threadIdx.x;
  if (idx >= BHS * ND) return;
  int d  = idx & (ND - 1);
  int s  = (idx >> 6) & (NS - 1);
  int bh = idx >> 17;              // ND*NS = 2^17
  int h  = bh % NH;
  int b  = bh / NH;
  float acc = 0.f;
  #pragma unroll
  for (int k = 0; k < NKER; ++k) {
    int ss = s + k - NKER / 2;
    if (ss >= 0 && ss < NS)
      acc += V[((size_t)bh * NS + ss) * ND + d] * mask[b * NS + ss] * cw[h * NKER + k];
  }
  out[idx] = acc;
}

// ---------------------------------------------------------------------------
// Fused YOSO attention. Weight transform uses Abramowitz-Stegun 4.4.45:
//   acos(a) ~= sqrt(1-a) * (a0 + a1*a + a2*a^2 + a3*a^3),  a in [0,1]
// (|err| ~1e-4 rad, an order below bf16 P-quantization), with the negative
// half folded via acos(x) = pi - acos(-x):  t = x>=0 ? 1-c/pi : c/pi.
// ---------------------------------------------------------------------------
__global__ __launch_bounds__(256) void yoso_attn(
    const bf16* __restrict__ Qn, const bf16* __restrict__ Kn,
    const bf16* __restrict__ Vmt, const float* __restrict__ mask,
    float* __restrict__ out) {
  __shared__ __align__(16) char lds[24 * 1024];
  char* kbuf = lds;                 // [64 keys][64 d] bf16, swizzled rows of 128B
  char* vbuf = lds + 8192;          // [64 d][64 keys] bf16, swizzled
  char* pbuf = lds + 16384;         // per-wave [16 q][64 keys] bf16

  int tid  = threadIdx.x;
  int wave = tid >> 6;
  int lane = tid & 63;
  int lo   = lane & 15;
  int hi   = lane >> 4;
  int bh   = blockIdx.y;
  int b    = bh / NH;
  int q0   = blockIdx.x * 64;

  const bf16* Qbh = Qn  + (size_t)bh * NS * ND;
  const bf16* Kbh = Kn  + (size_t)bh * NS * ND;
  const bf16* Vbh = Vmt + (size_t)bh * ND * NS;

  int qrow = q0 + wave * 16 + lo;
  bf16x8 aq0 = *(const bf16x8*)(Qbh + (size_t)qrow * ND + hi * 8);
  bf16x8 aq1 = *(const bf16x8*)(Qbh + (size_t)qrow * ND + 32 + hi * 8);

  f32x4 xacc[4];
  #pragma unroll
  for (int i = 0; i < 4; ++i) xacc[i] = (f32x4){0.f, 0.f, 0.f, 0.f};

  char* pw = pbuf + wave * (16 * 128);
  const float inv_pi = 0.3183098861837907f;

  for (int kt = 0; kt < NS / 64; ++kt) {
    __syncthreads();
    #pragma unroll
    for (int it = 0; it < 2; ++it) {
      int c    = tid + it * 256;
      int row  = c >> 3;
      int coff = (c & 7) * 16;
      int sw   = (row & 7) << 4;
      i32x4 kd = *(const i32x4*)((const char*)(Kbh + (size_t)(kt * 64 + row) * ND) + coff);
      *(i32x4*)(kbuf + row * 128 + (coff ^ sw)) = kd;
      i32x4 vd = *(const i32x4*)((const char*)(Vbh + (size_t)row * NS + kt * 64) + coff);
      *(i32x4*)(vbuf + row * 128 + (coff ^ sw)) = vd;
    }
    __syncthreads();

    // QK^T per 16-key column group, then weight transform, store P.
    #pragma unroll
    for (int cg = 0; cg < 4; ++cg) {
      f32x4 s = (f32x4){0.f, 0.f, 0.f, 0.f};
      int krow = cg * 16 + lo;
      const char* kbase = kbuf + krow * 128;
      int sw = (krow & 7) << 4;
      bf16x8 bk0 = *(const bf16x8*)(kbase + ((hi * 16) ^ sw));
      bf16x8 bk1 = *(const bf16x8*)(kbase + ((64 + hi * 16) ^ sw));
      s = mfma16x16x32_bf16(aq0, bk0, s);
      s = mfma16x16x32_bf16(aq1, bk1, s);
      #pragma unroll
      for (int r = 0; r < 4; ++r) {
        float x = s[r];
        float a = fminf(fabsf(x), 0.999999f);
        float sq = sqrtf(1.0f - a);
        float p = fmaf(fmaf(fmaf(-0.0187292994f, a, 0.0742610019f), a,
                            -0.2121143982f), a, 1.5707287788f);
        float u = sq * p * inv_pi;              // acos(a)/pi
        float t = (x >= 0.0f) ? (1.0f - u) : u; // 1 - acos(x)/pi
        float t2 = t * t, t4 = t2 * t2, w = t4 * t4;
        int prow = hi * 4 + r;
        int pcol = cg * 16 + lo;
        *(bf16*)(pw + prow * 128 + ((pcol * 2) ^ ((prow & 7) << 4))) = __float2bfloat16(w);
      }
    }

    // PV: X += P @ Vm  (K-dim = keys, 2 steps of 32).
    #pragma unroll
    for (int ks = 0; ks < 2; ++ks) {
      const char* pbase = pw + lo * 128;
      bf16x8 ap = *(const bf16x8*)(pbase + ((ks * 64 + hi * 16) ^ ((lo & 7) << 4)));
      #pragma unroll
      for (int dg = 0; dg < 4; ++dg) {
        int drow = dg * 16 + lo;
        const char* vbase = vbuf + drow * 128;
        bf16x8 bv = *(const bf16x8*)(vbase + ((ks * 64 + hi * 16) ^ ((drow & 7) << 4)));
        xacc[dg] = mfma16x16x32_bf16(ap, bv, xacc[dg]);
      }
    }
  }

  // Epilogue: query-side mask, L2 normalize per q-row, accumulate into out.
  #pragma unroll
  for (int r = 0; r < 4; ++r) {
    int row = q0 + wave * 16 + hi * 4 + r;
    float m = mask[b * NS + row];
    float vals[4];
    float ss = 0.f;
    #pragma unroll
    for (int dg = 0; dg < 4; ++dg) {
      float x = xacc[dg][r] * m;
      vals[dg] = x;
      ss += x * x;
    }
    #pragma unroll
    for (int mm = 1; mm < 16; mm <<= 1) ss += __shfl_xor(ss, mm);
    float scale = 1.0f / fmaxf(sqrtf(ss), 1e-12f);
    size_t base = ((size_t)bh * NS + row) * ND;
    #pragma unroll
    for (int dg = 0; dg < 4; ++dg) {
      int d = dg * 16 + lo;
      out[base + d] += vals[dg] * scale;
    }
  }
}

// ---------------------------------------------------------------------------
extern "C" void kernel_launch(void* const* d_in, const int* in_sizes, int n_in,
                              void* d_out, int out_size, void* d_ws, size_t ws_size,
                              hipStream_t stream) {
  const float* Q    = (const float*)d_in[0];
  const float* K    = (const float*)d_in[1];
  const float* V    = (const float*)d_in[2];
  const float* mask = (const float*)d_in[3];
  const float* cw   = (const float*)d_in[4];
  float* out = (float*)d_out;

  bf16* Qn  = (bf16*)d_ws;
  bf16* Kn  = Qn + (size_t)BHS * ND;
  bf16* Vmt = Kn + (size_t)BHS * ND;

  normalize_qk<<<2 * BHS / 4, 256, 0, stream>>>(Q, K, Qn, Kn);
  transpose_v<<<dim3(NS / 64, BH), 256, 0, stream>>>(V, mask, Vmt);
  conv_kernel<<<(BHS * ND + 255) / 256, 256, 0, stream>>>(V, mask, cw, out);
  yoso_attn<<<dim3(NS / 64, BH), 256, 0, stream>>>(Qn, Kn, Vmt, mask, out);
}

// Round 4
// 116.849 us; speedup vs baseline: 1.3356x; 1.3356x over previous
//
#include <hip/hip_runtime.h>
#include <hip/hip_bf16.h>
#include <math.h>

typedef __attribute__((ext_vector_type(4))) float f32x4;
typedef __attribute__((ext_vector_type(8))) short bf16x8;
typedef __attribute__((ext_vector_type(4))) int i32x4;

#define NB 2
#define NH 12
#define NS 2048
#define ND 64
#define NKER 9
#define BH (NB*NH)
#define BHS (NB*NH*NS)
#define NT (NS/64)

using bf16 = __hip_bfloat16;

__device__ __forceinline__ f32x4 mfma16x16x32_bf16(bf16x8 a, bf16x8 b, f32x4 c) {
  return __builtin_amdgcn_mfma_f32_16x16x32_bf16(a, b, c, 0, 0, 0);
}

// ---------------------------------------------------------------------------
// L2-normalize Q and K rows -> bf16. One wave per 64-elem row (lane == d).
// ---------------------------------------------------------------------------
__global__ void normalize_qk(const float* __restrict__ Q, const float* __restrict__ K,
                             bf16* __restrict__ Qn, bf16* __restrict__ Kn) {
  int wid  = (blockIdx.x * blockDim.x + threadIdx.x) >> 6;
  int lane = threadIdx.x & 63;
  if (wid >= 2 * BHS) return;
  const float* src; bf16* dst; int row;
  if (wid < BHS) { src = Q; dst = Qn; row = wid; }
  else           { src = K; dst = Kn; row = wid - BHS; }
  float v  = src[(size_t)row * ND + lane];
  float ss = v * v;
  #pragma unroll
  for (int m = 1; m < 64; m <<= 1) ss += __shfl_xor(ss, m);
  float scale = 1.0f / fmaxf(sqrtf(ss), 1e-12f);
  dst[(size_t)row * ND + lane] = __float2bfloat16(v * scale);
}

// ---------------------------------------------------------------------------
// Vm^T: (V * key-mask) transposed to [BH][D][S] in bf16.
// ---------------------------------------------------------------------------
__global__ void transpose_v(const float* __restrict__ V, const float* __restrict__ mask,
                            bf16* __restrict__ Vmt) {
  __shared__ bf16 tile[64][72];   // padded
  int bh = blockIdx.y;
  int b  = bh / NH;
  int s0 = blockIdx.x * 64;
  int tid = threadIdx.x;

  const float* src = V + ((size_t)bh * NS + s0) * ND;
  int r  = tid >> 2;
  int c0 = (tid & 3) * 16;
  float m = mask[b * NS + s0 + r];
  #pragma unroll
  for (int j = 0; j < 16; ++j)
    tile[r][c0 + j] = __float2bfloat16(src[(size_t)r * ND + c0 + j] * m);
  __syncthreads();

  bf16* dst = Vmt + (size_t)bh * ND * NS + s0;
  int d   = tid >> 2;
  int sc0 = (tid & 3) * 16;
  #pragma unroll
  for (int j = 0; j < 16; ++j)
    dst[(size_t)d * NS + sc0 + j] = tile[sc0 + j][d];
}

// ---------------------------------------------------------------------------
// Depthwise conv over seq axis (kernel 9), writes d_out (initialization).
// ---------------------------------------------------------------------------
__global__ void conv_kernel(const float* __restrict__ V, const float* __restrict__ mask,
                            const float* __restrict__ cw, float* __restrict__ out) {
  int idx = blockIdx.x * blockDim.x + threadIdx.x;
  if (idx >= BHS * ND) return;
  int d  = idx & (ND - 1);
  int s  = (idx >> 6) & (NS - 1);
  int bh = idx >> 17;              // ND*NS = 2^17
  int h  = bh % NH;
  int b  = bh / NH;
  float acc = 0.f;
  #pragma unroll
  for (int k = 0; k < NKER; ++k) {
    int ss = s + k - NKER / 2;
    if (ss >= 0 && ss < NS)
      acc += V[((size_t)bh * NS + ss) * ND + d] * mask[b * NS + ss] * cw[h * NKER + k];
  }
  out[idx] = acc;
}

// ---------------------------------------------------------------------------
// Fused YOSO attention, 2-phase pipelined:
//   per tile: [barrier] -> issue next-tile global loads (to regs, in flight
//   under compute) -> QK^T MFMA -> weight transform -> P (per-wave LDS) ->
//   PV MFMA -> write staged regs into the other LDS buffer.
// One barrier per tile; K/V LDS double-buffered (2 x 16 KB) + P (8 KB).
// Weight transform: acos(|x|)/pi via A-S 4.4.45 with 1/pi folded into the
// polynomial, raw v_sqrt_f32 (no fixup); negative half via acos(x)=pi-acos(-x).
// All LDS tiles XOR-swizzled: byte ^= (row&7)<<4.
// ---------------------------------------------------------------------------
__global__ __launch_bounds__(256) void yoso_attn(
    const bf16* __restrict__ Qn, const bf16* __restrict__ Kn,
    const bf16* __restrict__ Vmt, const float* __restrict__ mask,
    float* __restrict__ out) {
  __shared__ __align__(16) char lds[40 * 1024];
  // buffer b: K at lds + b*16384, V^T at lds + b*16384 + 8192; P at lds+32768.

  int tid  = threadIdx.x;
  int wave = tid >> 6;
  int lane = tid & 63;
  int lo   = lane & 15;
  int hi   = lane >> 4;
  int bh   = blockIdx.y;
  int b    = bh / NH;
  int q0   = blockIdx.x * 64;

  const bf16* Qbh = Qn  + (size_t)bh * NS * ND;
  const bf16* Kbh = Kn  + (size_t)bh * NS * ND;
  const bf16* Vbh = Vmt + (size_t)bh * ND * NS;

  int qrow = q0 + wave * 16 + lo;
  bf16x8 aq0 = *(const bf16x8*)(Qbh + (size_t)qrow * ND + hi * 8);
  bf16x8 aq1 = *(const bf16x8*)(Qbh + (size_t)qrow * ND + 32 + hi * 8);

  f32x4 xacc[4];
  #pragma unroll
  for (int i = 0; i < 4; ++i) xacc[i] = (f32x4){0.f, 0.f, 0.f, 0.f};

  // Staging addresses (thread-invariant across tiles).
  int row0 = tid >> 3,        coff0 = (tid & 7) * 16;
  int row1 = (tid + 256) >> 3, coff1 = ((tid + 256) & 7) * 16;
  int dst0 = row0 * 128 + (coff0 ^ ((row0 & 7) << 4));
  int dst1 = row1 * 128 + (coff1 ^ ((row1 & 7) << 4));
  const char* Ks0 = (const char*)(Kbh + (size_t)row0 * ND) + coff0;  // += 8192/tile
  const char* Ks1 = (const char*)(Kbh + (size_t)row1 * ND) + coff1;
  const char* Vs0 = (const char*)(Vbh + (size_t)row0 * NS) + coff0;  // += 128/tile
  const char* Vs1 = (const char*)(Vbh + (size_t)row1 * NS) + coff1;

  // Prologue: stage tile 0 into buffer 0 (no barrier needed yet).
  {
    i32x4 k0 = *(const i32x4*)(Ks0);
    i32x4 k1 = *(const i32x4*)(Ks1);
    i32x4 v0 = *(const i32x4*)(Vs0);
    i32x4 v1 = *(const i32x4*)(Vs1);
    *(i32x4*)(lds + dst0) = k0;
    *(i32x4*)(lds + dst1) = k1;
    *(i32x4*)(lds + 8192 + dst0) = v0;
    *(i32x4*)(lds + 8192 + dst1) = v1;
  }

  char* pw = lds + 32768 + wave * (16 * 128);
  i32x4 kr0, kr1, vr0, vr1;

  for (int kt = 0; kt < NT; ++kt) {
    __syncthreads();   // staged writes for tile kt visible; all reads of the
                       // buffer we'll overwrite this iter finished last iter.
    if (kt < NT - 1) { // issue next-tile loads; in flight under compute below
      kr0 = *(const i32x4*)(Ks0 + (size_t)(kt + 1) * 8192);
      kr1 = *(const i32x4*)(Ks1 + (size_t)(kt + 1) * 8192);
      vr0 = *(const i32x4*)(Vs0 + (size_t)(kt + 1) * 128);
      vr1 = *(const i32x4*)(Vs1 + (size_t)(kt + 1) * 128);
    }

    char* kb = lds + (kt & 1) * 16384;
    char* vb = kb + 8192;

    // QK^T per 16-key column group, transform, store P.
    #pragma unroll
    for (int cg = 0; cg < 4; ++cg) {
      f32x4 s = (f32x4){0.f, 0.f, 0.f, 0.f};
      int krow = cg * 16 + lo;
      const char* kbase = kb + krow * 128;
      int sw = (krow & 7) << 4;
      bf16x8 bk0 = *(const bf16x8*)(kbase + ((hi * 16) ^ sw));
      bf16x8 bk1 = *(const bf16x8*)(kbase + ((64 + hi * 16) ^ sw));
      s = mfma16x16x32_bf16(aq0, bk0, s);
      s = mfma16x16x32_bf16(aq1, bk1, s);
      #pragma unroll
      for (int r = 0; r < 4; ++r) {
        float x = s[r];
        float a = fminf(fabsf(x), 0.999999f);
        float sq = __builtin_amdgcn_sqrtf(1.0f - a);          // raw v_sqrt_f32
        float p = fmaf(fmaf(fmaf(-0.005961377f, a, 0.02363857f), a,
                            -0.06751758f), a, 0.49998939f);   // A-S 4.4.45 / pi
        float u = sq * p;                                     // acos(|x|)/pi
        float t = (x >= 0.0f) ? (1.0f - u) : u;               // 1 - acos(x)/pi
        float t2 = t * t, t4 = t2 * t2, w = t4 * t4;
        int prow = hi * 4 + r;
        int pcol = cg * 16 + lo;
        *(bf16*)(pw + prow * 128 + ((pcol * 2) ^ ((prow & 7) << 4))) = __float2bfloat16(w);
      }
    }

    // PV: X += P @ Vm  (K-dim = keys, 2 steps of 32).
    #pragma unroll
    for (int ks = 0; ks < 2; ++ks) {
      const char* pbase = pw + lo * 128;
      bf16x8 ap = *(const bf16x8*)(pbase + ((ks * 64 + hi * 16) ^ ((lo & 7) << 4)));
      #pragma unroll
      for (int dg = 0; dg < 4; ++dg) {
        int drow = dg * 16 + lo;
        const char* vbase = vb + drow * 128;
        bf16x8 bv = *(const bf16x8*)(vbase + ((ks * 64 + hi * 16) ^ ((drow & 7) << 4)));
        xacc[dg] = mfma16x16x32_bf16(ap, bv, xacc[dg]);
      }
    }

    // Write staged regs for tile kt+1 into the other buffer. Safe: any wave
    // past this iter's barrier has finished reading that buffer (tile kt-1).
    if (kt < NT - 1) {
      char* kbn = lds + ((kt + 1) & 1) * 16384;
      *(i32x4*)(kbn + dst0) = kr0;
      *(i32x4*)(kbn + dst1) = kr1;
      *(i32x4*)(kbn + 8192 + dst0) = vr0;
      *(i32x4*)(kbn + 8192 + dst1) = vr1;
    }
  }

  // Epilogue: query-side mask, L2 normalize per q-row, accumulate into out.
  #pragma unroll
  for (int r = 0; r < 4; ++r) {
    int row = q0 + wave * 16 + hi * 4 + r;
    float m = mask[b * NS + row];
    float vals[4];
    float ss = 0.f;
    #pragma unroll
    for (int dg = 0; dg < 4; ++dg) {
      float x = xacc[dg][r] * m;
      vals[dg] = x;
      ss += x * x;
    }
    #pragma unroll
    for (int mm = 1; mm < 16; mm <<= 1) ss += __shfl_xor(ss, mm);
    float scale = 1.0f / fmaxf(sqrtf(ss), 1e-12f);
    size_t base = ((size_t)bh * NS + row) * ND;
    #pragma unroll
    for (int dg = 0; dg < 4; ++dg) {
      int d = dg * 16 + lo;
      out[base + d] += vals[dg] * scale;
    }
  }
}

// ---------------------------------------------------------------------------
extern "C" void kernel_launch(void* const* d_in, const int* in_sizes, int n_in,
                              void* d_out, int out_size, void* d_ws, size_t ws_size,
                              hipStream_t stream) {
  const float* Q    = (const float*)d_in[0];
  const float* K    = (const float*)d_in[1];
  const float* V    = (const float*)d_in[2];
  const float* mask = (const float*)d_in[3];
  const float* cw   = (const float*)d_in[4];
  float* out = (float*)d_out;

  bf16* Qn  = (bf16*)d_ws;
  bf16* Kn  = Qn + (size_t)BHS * ND;
  bf16* Vmt = Kn + (size_t)BHS * ND;

  normalize_qk<<<2 * BHS / 4, 256, 0, stream>>>(Q, K, Qn, Kn);
  transpose_v<<<dim3(NS / 64, BH), 256, 0, stream>>>(V, mask, Vmt);
  conv_kernel<<<(BHS * ND + 255) / 256, 256, 0, stream>>>(V, mask, cw, out);
  yoso_attn<<<dim3(NS / 64, BH), 256, 0, stream>>>(Qn, Kn, Vmt, mask, out);
}

// Round 5
// 93.269 us; speedup vs baseline: 1.6732x; 1.2528x over previous
//
#include <hip/hip_runtime.h>
#include <hip/hip_bf16.h>
#include <math.h>

typedef __attribute__((ext_vector_type(4))) float f32x4;
typedef __attribute__((ext_vector_type(8))) short bf16x8;
typedef __attribute__((ext_vector_type(4))) int i32x4;

#define NB 2
#define NH 12
#define NS 2048
#define ND 64
#define NKER 9
#define BH (NB*NH)
#define BHS (NB*NH*NS)
#define NT (NS/64)

using bf16 = __hip_bfloat16;

__device__ __forceinline__ f32x4 mfma16x16x32_bf16(bf16x8 a, bf16x8 b, f32x4 c) {
  return __builtin_amdgcn_mfma_f32_16x16x32_bf16(a, b, c, 0, 0, 0);
}

// ---------------------------------------------------------------------------
// L2-normalize Q and K rows -> bf16. One wave per 64-elem row (lane == d).
// ---------------------------------------------------------------------------
__global__ void normalize_qk(const float* __restrict__ Q, const float* __restrict__ K,
                             bf16* __restrict__ Qn, bf16* __restrict__ Kn) {
  int wid  = (blockIdx.x * blockDim.x + threadIdx.x) >> 6;
  int lane = threadIdx.x & 63;
  if (wid >= 2 * BHS) return;
  const float* src; bf16* dst; int row;
  if (wid < BHS) { src = Q; dst = Qn; row = wid; }
  else           { src = K; dst = Kn; row = wid - BHS; }
  float v  = src[(size_t)row * ND + lane];
  float ss = v * v;
  #pragma unroll
  for (int m = 1; m < 64; m <<= 1) ss += __shfl_xor(ss, m);
  float scale = 1.0f / fmaxf(sqrtf(ss), 1e-12f);
  dst[(size_t)row * ND + lane] = __float2bfloat16(v * scale);
}

// ---------------------------------------------------------------------------
// Fused conv + V^T: load masked-V halo tile (72 rows) into padded LDS once;
// emit depthwise conv -> out AND bf16 transposed Vm -> Vmt.
// Pad 68: row stride = 4 mod 32 banks -> conv's column-pattern reads spread.
// ---------------------------------------------------------------------------
__global__ __launch_bounds__(256) void conv_vt(
    const float* __restrict__ V, const float* __restrict__ mask,
    const float* __restrict__ cw, float* __restrict__ out, bf16* __restrict__ Vmt) {
  __shared__ float tile[72][68];
  __shared__ float wsm[NKER];
  int bh = blockIdx.y, b = bh / NH, h = bh % NH;
  int s0 = blockIdx.x * 64;
  int tid = threadIdx.x;
  if (tid < NKER) wsm[tid] = cw[h * NKER + tid];

  int r  = tid >> 2;
  int c0 = (tid & 3) * 16;
  #pragma unroll
  for (int pass = 0; pass < 2; ++pass) {
    int rr = r + pass * 64;
    if (pass == 0 || tid < 32) {
      int gs = s0 - NKER / 2 + rr;
      bool ok = (gs >= 0 && gs < NS);
      float m = ok ? mask[b * NS + gs] : 0.f;
      #pragma unroll
      for (int j = 0; j < 16; ++j)
        tile[rr][c0 + j] = ok ? V[((size_t)bh * NS + gs) * ND + c0 + j] * m : 0.f;
    }
  }
  __syncthreads();

  // conv: thread owns seq row s = tid>>2, cols c0..c0+15
  {
    int s = tid >> 2;
    float acc[16];
    #pragma unroll
    for (int j = 0; j < 16; ++j) acc[j] = 0.f;
    #pragma unroll
    for (int k = 0; k < NKER; ++k) {
      float w = wsm[k];
      #pragma unroll
      for (int j = 0; j < 16; ++j) acc[j] += tile[s + k][c0 + j] * w;
    }
    float* dst = out + ((size_t)bh * NS + s0 + s) * ND + c0;
    #pragma unroll
    for (int j = 0; j < 16; ++j) dst[j] = acc[j];
  }
  // transpose: thread owns d = tid>>2, seq chunk c0..c0+15 (center rows +4)
  {
    int d = tid >> 2;
    bf16* dst = Vmt + (size_t)bh * ND * NS + (size_t)d * NS + s0 + c0;
    #pragma unroll
    for (int j = 0; j < 16; ++j)
      dst[j] = __float2bfloat16(tile[NKER / 2 + c0 + j][d]);
  }
}

// ---------------------------------------------------------------------------
// Fused YOSO attention, 2-phase pipelined, 8 waves = 4 q-subtiles x 2 key
// halves. Each wave: 16 q-rows x 32 keys of each 64-key tile -> 6144 waves
// (6/SIMD) for VALU-issue overlap. Key-half partial X combined via LDS.
// Weight transform: acos/pi via A-S 4.4.45 with 1/pi folded in, raw v_sqrt.
// All LDS tiles XOR-swizzled: byte ^= (row&7)<<4.
// ---------------------------------------------------------------------------
__global__ __launch_bounds__(512) void yoso_attn(
    const bf16* __restrict__ Qn, const bf16* __restrict__ Kn,
    const bf16* __restrict__ Vmt, const float* __restrict__ mask,
    float* __restrict__ out) {
  __shared__ __align__(16) char lds[48 * 1024];
  // buffer b: K at b*16384, V^T at b*16384+8192; P (per wave 2KB) at 32768.

  int tid  = threadIdx.x;
  int wave = tid >> 6;
  int lane = tid & 63;
  int lo   = lane & 15;
  int hi   = lane >> 4;
  int qsub = wave >> 1;
  int kh   = wave & 1;
  int bh   = blockIdx.y;
  int b    = bh / NH;
  int q0   = blockIdx.x * 64;

  const bf16* Qbh = Qn  + (size_t)bh * NS * ND;
  const bf16* Kbh = Kn  + (size_t)bh * NS * ND;
  const bf16* Vbh = Vmt + (size_t)bh * ND * NS;

  int qrow = q0 + qsub * 16 + lo;
  bf16x8 aq0 = *(const bf16x8*)(Qbh + (size_t)qrow * ND + hi * 8);
  bf16x8 aq1 = *(const bf16x8*)(Qbh + (size_t)qrow * ND + 32 + hi * 8);

  f32x4 xacc[4];
  #pragma unroll
  for (int i = 0; i < 4; ++i) xacc[i] = (f32x4){0.f, 0.f, 0.f, 0.f};

  // Staging: 512 threads, 1 K-chunk + 1 V-chunk (16B) each per tile.
  int row0 = tid >> 3, coff0 = (tid & 7) * 16;
  int dst0 = row0 * 128 + (coff0 ^ ((row0 & 7) << 4));
  const char* Ks0 = (const char*)(Kbh + (size_t)row0 * ND) + coff0;  // +8192/tile
  const char* Vs0 = (const char*)(Vbh + (size_t)row0 * NS) + coff0;  // +128/tile

  *(i32x4*)(lds + dst0)        = *(const i32x4*)Ks0;
  *(i32x4*)(lds + 8192 + dst0) = *(const i32x4*)Vs0;

  char* pw = lds + 32768 + wave * 2048;
  i32x4 kr, vr;

  for (int kt = 0; kt < NT; ++kt) {
    __syncthreads();
    if (kt < NT - 1) {
      kr = *(const i32x4*)(Ks0 + (size_t)(kt + 1) * 8192);
      vr = *(const i32x4*)(Vs0 + (size_t)(kt + 1) * 128);
    }
    char* kb = lds + (kt & 1) * 16384;
    char* vb = kb + 8192;

    // QK^T on this wave's 2 local 16-key groups, transform, store P.
    #pragma unroll
    for (int cgl = 0; cgl < 2; ++cgl) {
      int cg   = kh * 2 + cgl;
      f32x4 s  = (f32x4){0.f, 0.f, 0.f, 0.f};
      int krow = cg * 16 + lo;
      const char* kbase = kb + krow * 128;
      int sw = (krow & 7) << 4;
      bf16x8 bk0 = *(const bf16x8*)(kbase + ((hi * 16) ^ sw));
      bf16x8 bk1 = *(const bf16x8*)(kbase + ((64 + hi * 16) ^ sw));
      s = mfma16x16x32_bf16(aq0, bk0, s);
      s = mfma16x16x32_bf16(aq1, bk1, s);
      #pragma unroll
      for (int r = 0; r < 4; ++r) {
        float x = s[r];
        float a = fminf(fabsf(x), 0.999999f);
        float sq = __builtin_amdgcn_sqrtf(1.0f - a);
        float p = fmaf(fmaf(fmaf(-0.005961377f, a, 0.02363857f), a,
                            -0.06751758f), a, 0.49998939f);   // A-S 4.4.45 / pi
        float u = sq * p;                                     // acos(|x|)/pi
        float t = (x >= 0.0f) ? (1.0f - u) : u;               // 1 - acos(x)/pi
        float t2 = t * t, t4 = t2 * t2, w = t4 * t4;
        int prow = hi * 4 + r;
        int pcol = cgl * 16 + lo;   // local key col (global kh*32 + pcol)
        *(bf16*)(pw + prow * 128 + ((pcol * 2) ^ ((prow & 7) << 4))) = __float2bfloat16(w);
      }
    }

    // PV over this wave's 32 keys (one K=32 MFMA step).
    {
      const char* pbase = pw + lo * 128;
      bf16x8 ap = *(const bf16x8*)(pbase + ((hi * 16) ^ ((lo & 7) << 4)));
      #pragma unroll
      for (int dg = 0; dg < 4; ++dg) {
        int drow = dg * 16 + lo;
        const char* vbase = vb + drow * 128;
        bf16x8 bv = *(const bf16x8*)(vbase + ((kh * 64 + hi * 16) ^ ((drow & 7) << 4)));
        xacc[dg] = mfma16x16x32_bf16(ap, bv, xacc[dg]);
      }
    }

    if (kt < NT - 1) {
      char* kbn = lds + ((kt + 1) & 1) * 16384;
      *(i32x4*)(kbn + dst0)        = kr;
      *(i32x4*)(kbn + 8192 + dst0) = vr;
    }
  }

  // Combine key halves (reuse P region), then mask + L2-normalize + store.
  __syncthreads();
  float* cmb = (float*)(lds + 32768);
  if (kh == 1) {
    #pragma unroll
    for (int r = 0; r < 4; ++r)
      #pragma unroll
      for (int dg = 0; dg < 4; ++dg)
        cmb[qsub * 1024 + (hi * 4 + r) * 64 + dg * 16 + lo] = xacc[dg][r];
  }
  __syncthreads();
  if (kh == 0) {
    #pragma unroll
    for (int r = 0; r < 4; ++r) {
      int row = q0 + qsub * 16 + hi * 4 + r;
      float m = mask[b * NS + row];
      float vals[4];
      float ss = 0.f;
      #pragma unroll
      for (int dg = 0; dg < 4; ++dg) {
        float x = (xacc[dg][r] + cmb[qsub * 1024 + (hi * 4 + r) * 64 + dg * 16 + lo]) * m;
        vals[dg] = x;
        ss += x * x;
      }
      #pragma unroll
      for (int mm = 1; mm < 16; mm <<= 1) ss += __shfl_xor(ss, mm);
      float scale = 1.0f / fmaxf(sqrtf(ss), 1e-12f);
      size_t base = ((size_t)bh * NS + row) * ND;
      #pragma unroll
      for (int dg = 0; dg < 4; ++dg)
        out[base + dg * 16 + lo] += vals[dg] * scale;
    }
  }
}

// ---------------------------------------------------------------------------
extern "C" void kernel_launch(void* const* d_in, const int* in_sizes, int n_in,
                              void* d_out, int out_size, void* d_ws, size_t ws_size,
                              hipStream_t stream) {
  const float* Q    = (const float*)d_in[0];
  const float* K    = (const float*)d_in[1];
  const float* V    = (const float*)d_in[2];
  const float* mask = (const float*)d_in[3];
  const float* cw   = (const float*)d_in[4];
  float* out = (float*)d_out;

  bf16* Qn  = (bf16*)d_ws;
  bf16* Kn  = Qn + (size_t)BHS * ND;
  bf16* Vmt = Kn + (size_t)BHS * ND;

  normalize_qk<<<2 * BHS / 4, 256, 0, stream>>>(Q, K, Qn, Kn);
  conv_vt<<<dim3(NS / 64, BH), 256, 0, stream>>>(V, mask, cw, out, Vmt);
  yoso_attn<<<dim3(NS / 64, BH), 512, 0, stream>>>(Qn, Kn, Vmt, mask, out);
}

// Round 6
// 89.543 us; speedup vs baseline: 1.7428x; 1.0416x over previous
//
#include <hip/hip_runtime.h>
#include <hip/hip_bf16.h>
#include <math.h>

typedef __attribute__((ext_vector_type(4)))  float f32x4;
typedef __attribute__((ext_vector_type(16))) float f32x16;
typedef __attribute__((ext_vector_type(8)))  short bf16x8;
typedef __attribute__((ext_vector_type(4)))  int   i32x4;

#define NB 2
#define NH 12
#define NS 2048
#define ND 64
#define NKER 9
#define BH (NB*NH)
#define BHS (NB*NH*NS)
#define NT (NS/64)

using bf16 = __hip_bfloat16;

__device__ __forceinline__ f32x16 mfma32(bf16x8 a, bf16x8 b, f32x16 c) {
  return __builtin_amdgcn_mfma_f32_32x32x16_bf16(a, b, c, 0, 0, 0);
}

// RNE float->bf16, no NaN path (inputs are finite by construction).
__device__ __forceinline__ unsigned short bf16rne(float f) {
  unsigned u = __builtin_bit_cast(unsigned, f);
  u += 0x7FFFu + ((u >> 16) & 1u);
  return (unsigned short)(u >> 16);
}

// ---------------------------------------------------------------------------
// prep: per (bh, 64-seq tile): depthwise conv -> out, masked V^T bf16 -> Vmt,
// and L2-normalized K -> Kn. One pass over K/V.
// ---------------------------------------------------------------------------
__global__ __launch_bounds__(256) void prep(
    const float* __restrict__ K, const float* __restrict__ V,
    const float* __restrict__ mask, const float* __restrict__ cw,
    float* __restrict__ out, bf16* __restrict__ Kn, bf16* __restrict__ Vmt) {
  __shared__ float tile[72][68];
  __shared__ float wsm[NKER];
  int bh = blockIdx.y, b = bh / NH, h = bh % NH;
  int s0 = blockIdx.x * 64;
  int tid = threadIdx.x;
  if (tid < NKER) wsm[tid] = cw[h * NKER + tid];

  int r  = tid >> 2;
  int c0 = (tid & 3) * 16;

  // --- K-normalize rows (no LDS; shfl within 4-lane row groups)
  {
    const float* Kr = K + ((size_t)bh * NS + s0 + r) * ND + c0;
    float v[16]; float ss = 0.f;
    #pragma unroll
    for (int j = 0; j < 16; ++j) { v[j] = Kr[j]; ss += v[j] * v[j]; }
    ss += __shfl_xor(ss, 1); ss += __shfl_xor(ss, 2);
    float sc = rsqrtf(fmaxf(ss, 1e-24f));
    bf16x8 o0, o1;
    #pragma unroll
    for (int j = 0; j < 8; ++j) {
      o0[j] = (short)bf16rne(v[j] * sc);
      o1[j] = (short)bf16rne(v[8 + j] * sc);
    }
    bf16* dst = Kn + ((size_t)bh * NS + s0 + r) * ND + c0;
    *(bf16x8*)dst = o0; *(bf16x8*)(dst + 8) = o1;
  }

  // --- masked V halo tile
  #pragma unroll
  for (int pass = 0; pass < 2; ++pass) {
    int rr = r + pass * 64;
    if (pass == 0 || tid < 32) {
      int gs = s0 - NKER / 2 + rr;
      bool ok = (gs >= 0 && gs < NS);
      float m = ok ? mask[b * NS + gs] : 0.f;
      #pragma unroll
      for (int j = 0; j < 16; ++j)
        tile[rr][c0 + j] = ok ? V[((size_t)bh * NS + gs) * ND + c0 + j] * m : 0.f;
    }
  }
  __syncthreads();

  // --- conv
  {
    float acc[16];
    #pragma unroll
    for (int j = 0; j < 16; ++j) acc[j] = 0.f;
    #pragma unroll
    for (int k = 0; k < NKER; ++k) {
      float w = wsm[k];
      #pragma unroll
      for (int j = 0; j < 16; ++j) acc[j] += tile[r + k][c0 + j] * w;
    }
    float* dst = out + ((size_t)bh * NS + s0 + r) * ND + c0;
    #pragma unroll
    for (int j = 0; j < 16; ++j) dst[j] = acc[j];
  }
  // --- V^T (masked, bf16)
  {
    bf16x8 o0, o1;
    #pragma unroll
    for (int j = 0; j < 8; ++j) {
      o0[j] = (short)bf16rne(tile[NKER / 2 + c0 + j][r]);
      o1[j] = (short)bf16rne(tile[NKER / 2 + c0 + 8 + j][r]);
    }
    bf16* dst = Vmt + (size_t)bh * ND * NS + (size_t)r * NS + s0 + c0;
    *(bf16x8*)dst = o0; *(bf16x8*)(dst + 8) = o1;
  }
}

// ---------------------------------------------------------------------------
// Fused YOSO attention, 32x32x16 MFMA. Block = 64q x 64k tile, 4 waves =
// 2 qsub (32 q-rows) x 2 key-halves (32 keys). Q normalized in prologue.
// 1-barrier/tile double-buffered K/V staging (reg-staged). P per wave in LDS
// [32q][32k] bf16, row-swizzled byte ^= ((q>>2)&3)<<4. K/V tiles swizzled
// byte ^= (row&7)<<4. Epilogue: key-half combine via LDS, mask, L2-norm, +=.
// C-layout (verified): col=lane&31, row=(reg&3)+8*(reg>>2)+4*(lane>>5).
// ---------------------------------------------------------------------------
__global__ __launch_bounds__(256) void yoso_attn(
    const float* __restrict__ Q, const bf16* __restrict__ Kn,
    const bf16* __restrict__ Vmt, const float* __restrict__ mask,
    float* __restrict__ out) {
  __shared__ __align__(16) char lds[40 * 1024];
  // buf b: K at b*16384 (8KB), V^T at b*16384+8192 (8KB); P at 32768 (4x2KB).

  int tid  = threadIdx.x;
  int wave = tid >> 6;
  int lane = tid & 63;
  int ql   = lane & 31;
  int c    = lane >> 5;
  int qsub = wave >> 1;
  int kh   = wave & 1;
  int bh   = blockIdx.y;
  int b    = bh / NH;
  int q0   = blockIdx.x * 64;

  const bf16* Kbh = Kn  + (size_t)bh * NS * ND;
  const bf16* Vbh = Vmt + (size_t)bh * ND * NS;

  // ---- Q load + L2-normalize + A-fragments (row=ql, k-octet=c)
  bf16x8 aq[4];
  {
    int qrow = q0 + qsub * 32 + ql;
    const float* Qr = Q + ((size_t)bh * NS + qrow) * ND;
    float qv[32]; float ss = 0.f;
    #pragma unroll
    for (int t = 0; t < 4; ++t) {
      f32x4 a0 = *(const f32x4*)(Qr + t * 16 + c * 8);
      f32x4 a1 = *(const f32x4*)(Qr + t * 16 + c * 8 + 4);
      #pragma unroll
      for (int j = 0; j < 4; ++j) {
        qv[t * 8 + j] = a0[j]; qv[t * 8 + 4 + j] = a1[j];
        ss += a0[j] * a0[j] + a1[j] * a1[j];
      }
    }
    ss += __shfl_xor(ss, 32);
    float sc = rsqrtf(fmaxf(ss, 1e-24f));
    #pragma unroll
    for (int t = 0; t < 4; ++t)
      #pragma unroll
      for (int j = 0; j < 8; ++j)
        aq[t][j] = (short)bf16rne(qv[t * 8 + j] * sc);
  }

  f32x16 xacc[2] = {};

  // ---- staging addresses (256 threads: 2 K-chunks + 2 V-chunks of 16B each)
  int srow = tid >> 3;              // 0..31
  int scol = (tid & 7) * 16;
  int sw   = (srow & 7) << 4;       // (srow+32)&7 == srow&7
  int d0 = srow * 128 + (scol ^ sw);
  int d1 = (srow + 32) * 128 + (scol ^ sw);
  const char* KsA = (const char*)Kbh + (size_t)srow * 128 + scol;
  const char* KsB = (const char*)Kbh + (size_t)(srow + 32) * 128 + scol;
  const char* VsA = (const char*)Vbh + (size_t)srow * (NS * 2) + scol;
  const char* VsB = (const char*)Vbh + (size_t)(srow + 32) * (NS * 2) + scol;

  // prologue: stage tile 0 into buffer 0
  *(i32x4*)(lds + d0)        = *(const i32x4*)KsA;
  *(i32x4*)(lds + d1)        = *(const i32x4*)KsB;
  *(i32x4*)(lds + 8192 + d0) = *(const i32x4*)VsA;
  *(i32x4*)(lds + 8192 + d1) = *(const i32x4*)VsB;

  // ---- hoisted read offsets (buffer-relative)
  int krow = kh * 32 + ql;
  int ksw  = (krow & 7) << 4;
  int kboff[4];
  #pragma unroll
  for (int t = 0; t < 4; ++t) kboff[t] = krow * 128 + ((t * 32 + c * 16) ^ ksw);
  int pslot_r = ((ql >> 2) & 3) << 4;
  int poff[2];
  #pragma unroll
  for (int ks = 0; ks < 2; ++ks) poff[ks] = ql * 64 + ((ks * 32 + c * 16) ^ pslot_r);
  int bvoff[2][2];
  #pragma unroll
  for (int dt = 0; dt < 2; ++dt) {
    int drow = dt * 32 + ql;
    int vsw  = (drow & 7) << 4;
    #pragma unroll
    for (int ks = 0; ks < 2; ++ks)
      bvoff[dt][ks] = drow * 128 + ((kh * 64 + ks * 32 + c * 16) ^ vsw);
  }

  char* pw = lds + 32768 + wave * 2048;
  i32x4 kA, kB, vA, vB;

  for (int kt = 0; kt < NT; ++kt) {
    __syncthreads();
    if (kt < NT - 1) {
      kA = *(const i32x4*)(KsA + (size_t)(kt + 1) * 8192);
      kB = *(const i32x4*)(KsB + (size_t)(kt + 1) * 8192);
      vA = *(const i32x4*)(VsA + (size_t)(kt + 1) * 128);
      vB = *(const i32x4*)(VsB + (size_t)(kt + 1) * 128);
    }
    char* kb = lds + (kt & 1) * 16384;
    char* vb = kb + 8192;

    // QK^T: 32q x 32k, D=64 in 4 K=16 slices
    f32x16 s{};
    #pragma unroll
    for (int t = 0; t < 4; ++t) {
      bf16x8 bk = *(const bf16x8*)(kb + kboff[t]);
      s = mfma32(aq[t], bk, s);
    }

    // transform + P store
    #pragma unroll
    for (int r = 0; r < 16; ++r) {
      float x  = s[r];
      float a  = fminf(fabsf(x), 0.999999f);
      float sq = __builtin_amdgcn_sqrtf(1.0f - a);
      float p  = fmaf(fmaf(fmaf(-0.005961377f, a, 0.02363857f), a,
                           -0.06751758f), a, 0.49998939f);   // acos/pi poly
      float u  = sq * p;
      float t1 = (x >= 0.0f) ? (1.0f - u) : u;
      float t2 = t1 * t1, t4 = t2 * t2, w = t4 * t4;
      int q_loc = (r & 3) + 8 * (r >> 2) + 4 * c;
      *(short*)(pw + q_loc * 64 + ((ql * 2) ^ ((((q_loc >> 2) & 3)) << 4))) =
          (short)bf16rne(w);
    }

    // PV: X[32q][64d] += P[32q][32k] * V^T, 2 K=16 slices x 2 d-tiles
    #pragma unroll
    for (int ks = 0; ks < 2; ++ks) {
      bf16x8 ap = *(const bf16x8*)(pw + poff[ks]);
      #pragma unroll
      for (int dt = 0; dt < 2; ++dt) {
        bf16x8 bv = *(const bf16x8*)(vb + bvoff[dt][ks]);
        xacc[dt] = mfma32(ap, bv, xacc[dt]);
      }
    }

    if (kt < NT - 1) {
      char* nb = lds + ((kt + 1) & 1) * 16384;
      *(i32x4*)(nb + d0)        = kA;
      *(i32x4*)(nb + d1)        = kB;
      *(i32x4*)(nb + 8192 + d0) = vA;
      *(i32x4*)(nb + 8192 + d1) = vB;
    }
  }

  // ---- epilogue: combine key halves via LDS (buf0 region is free), norm, +=
  float* cmb = (float*)lds;
  if (kh == 1) {
    #pragma unroll
    for (int dt = 0; dt < 2; ++dt)
      #pragma unroll
      for (int r = 0; r < 16; ++r) {
        int q_loc = (r & 3) + 8 * (r >> 2) + 4 * c;
        cmb[qsub * 2048 + q_loc * 64 + dt * 32 + ql] = xacc[dt][r];
      }
  }
  __syncthreads();
  if (kh == 0) {
    #pragma unroll
    for (int r = 0; r < 16; ++r) {
      int q_loc = (r & 3) + 8 * (r >> 2) + 4 * c;
      int row = q0 + qsub * 32 + q_loc;
      float m = mask[b * NS + row];
      float x0 = (xacc[0][r] + cmb[qsub * 2048 + q_loc * 64 + ql]) * m;
      float x1 = (xacc[1][r] + cmb[qsub * 2048 + q_loc * 64 + 32 + ql]) * m;
      float s2 = x0 * x0 + x1 * x1;
      #pragma unroll
      for (int mm = 1; mm < 32; mm <<= 1) s2 += __shfl_xor(s2, mm);
      float sc = rsqrtf(fmaxf(s2, 1e-24f));
      size_t base = ((size_t)bh * NS + row) * ND;
      out[base + ql]      += x0 * sc;
      out[base + 32 + ql] += x1 * sc;
    }
  }
}

// ---------------------------------------------------------------------------
extern "C" void kernel_launch(void* const* d_in, const int* in_sizes, int n_in,
                              void* d_out, int out_size, void* d_ws, size_t ws_size,
                              hipStream_t stream) {
  const float* Q    = (const float*)d_in[0];
  const float* K    = (const float*)d_in[1];
  const float* V    = (const float*)d_in[2];
  const float* mask = (const float*)d_in[3];
  const float* cw   = (const float*)d_in[4];
  float* out = (float*)d_out;

  bf16* Kn  = (bf16*)d_ws;
  bf16* Vmt = Kn + (size_t)BHS * ND;

  prep<<<dim3(NS / 64, BH), 256, 0, stream>>>(K, V, mask, cw, out, Kn, Vmt);
  yoso_attn<<<dim3(NS / 64, BH), 256, 0, stream>>>(Q, Kn, Vmt, mask, out);
}